// Round 1
// baseline (2606.717 us; speedup 1.0000x reference)
//
#include <hip/hip_runtime.h>
#include <stdint.h>

// ---------------------------------------------------------------------------
// Dwtpool fused pipeline, MI355X gfx950.
// All feature maps live in workspace as NHWC bf16; convs are implicit GEMMs
// on a 128x128-tile MFMA kernel (16x16x32 bf16, 4 waves, BK=32, reg-staged).
// ---------------------------------------------------------------------------

typedef __attribute__((ext_vector_type(8))) short bf16x8;
typedef __attribute__((ext_vector_type(4))) float f32x4;

#define EPS_ 1e-5f

__device__ __forceinline__ float bf2f(unsigned short u) {
  union { unsigned int u; float f; } c; c.u = ((unsigned int)u) << 16; return c.f;
}
__device__ __forceinline__ unsigned short f2bf(float f) {
  union { float f; unsigned int u; } c; c.f = f;
  return (unsigned short)((c.u + 0x7fffu + ((c.u >> 16) & 1u)) >> 16);
}
__device__ __forceinline__ void unpack8(uint4 v, float* f) {
  f[0]=bf2f((unsigned short)(v.x&0xffffu)); f[1]=bf2f((unsigned short)(v.x>>16));
  f[2]=bf2f((unsigned short)(v.y&0xffffu)); f[3]=bf2f((unsigned short)(v.y>>16));
  f[4]=bf2f((unsigned short)(v.z&0xffffu)); f[5]=bf2f((unsigned short)(v.z>>16));
  f[6]=bf2f((unsigned short)(v.w&0xffffu)); f[7]=bf2f((unsigned short)(v.w>>16));
}
__device__ __forceinline__ uint4 pack8(const float* f) {
  uint4 v;
  v.x = (unsigned)f2bf(f[0]) | ((unsigned)f2bf(f[1])<<16);
  v.y = (unsigned)f2bf(f[2]) | ((unsigned)f2bf(f[3])<<16);
  v.z = (unsigned)f2bf(f[4]) | ((unsigned)f2bf(f[5])<<16);
  v.w = (unsigned)f2bf(f[6]) | ((unsigned)f2bf(f[7])<<16);
  return v;
}

// --- weight repack: OIHW f32 -> [tap][O][I] bf16 ---------------------------
__global__ void k_repack(const float* __restrict__ src, unsigned short* __restrict__ dst,
                         int O, int I, int T) {
  int gid = blockIdx.x * 256 + threadIdx.x;
  if (gid >= O * I * T) return;
  int i = gid % I; int r = gid / I; int o = r % O; int t = r / O;
  dst[gid] = f2bf(src[((size_t)(o * I + i)) * T + t]);
}

// --- x: NCHW f32 -> NHWC bf16 [16][128][128][256] --------------------------
__global__ void k_transpose_x(const float* __restrict__ x, unsigned short* __restrict__ xh) {
  int by = blockIdx.x; int b = by >> 7; int y = by & 127;
  int tid = threadIdx.x;
  __shared__ unsigned short lds[32 * 129];
  for (int c0 = 0; c0 < 256; c0 += 32) {
    #pragma unroll
    for (int i = 0; i < 16; ++i) {
      int e = i * 256 + tid; int ci = e >> 7, xx = e & 127;
      float v = x[(((size_t)b * 256 + c0 + ci) * 128 + y) * 128 + xx];
      lds[ci * 129 + xx] = f2bf(v);
    }
    __syncthreads();
    #pragma unroll
    for (int i2 = 0; i2 < 2; ++i2) {
      int e = i2 * 256 + tid; int pix = e >> 2, q = e & 3;
      unsigned int w0 = 0, w1 = 0, w2 = 0, w3 = 0;
      w0 = (unsigned)lds[(q*8+0)*129 + pix] | ((unsigned)lds[(q*8+1)*129 + pix] << 16);
      w1 = (unsigned)lds[(q*8+2)*129 + pix] | ((unsigned)lds[(q*8+3)*129 + pix] << 16);
      w2 = (unsigned)lds[(q*8+4)*129 + pix] | ((unsigned)lds[(q*8+5)*129 + pix] << 16);
      w3 = (unsigned)lds[(q*8+6)*129 + pix] | ((unsigned)lds[(q*8+7)*129 + pix] << 16);
      uint4 v; v.x = w0; v.y = w1; v.z = w2; v.w = w3;
      *(uint4*)&xh[(((size_t)b * 128 + y) * 128 + pix) * 256 + c0 + q * 8] = v;
    }
    __syncthreads();
  }
}

// --- maxpool 2x2 on xh -> cat channels [1280..1536) ------------------------
__global__ void k_maxpool(const unsigned short* __restrict__ xh, unsigned short* __restrict__ cat) {
  int gid = blockIdx.x * 256 + threadIdx.x;        // 16*4096*32
  int cq = gid & 31; int pix = gid >> 5;
  int bb = pix >> 12; int yx = pix & 4095;
  int y = yx >> 6, xx2 = yx & 63;
  size_t base = (((size_t)bb * 128 + 2 * y) * 128 + 2 * xx2) * 256 + cq * 8;
  uint4 v00 = *(const uint4*)(xh + base);
  uint4 v01 = *(const uint4*)(xh + base + 256);
  uint4 v10 = *(const uint4*)(xh + base + 32768);
  uint4 v11 = *(const uint4*)(xh + base + 32768 + 256);
  float a[8], b8[8], c8[8], d8[8], m8[8];
  unpack8(v00, a); unpack8(v01, b8); unpack8(v10, c8); unpack8(v11, d8);
  #pragma unroll
  for (int j = 0; j < 8; ++j) m8[j] = fmaxf(fmaxf(a[j], b8[j]), fmaxf(c8[j], d8[j]));
  *(uint4*)(cat + ((size_t)bb * 4096 + yx) * 1536 + 1280 + cq * 8) = pack8(m8);
}

// --- haar DWT: rbn [16][128][128][64] -> cat channels [0..256) -------------
__global__ void k_haar(const unsigned short* __restrict__ rbn, unsigned short* __restrict__ cat) {
  int gid = blockIdx.x * 256 + threadIdx.x;        // 16*4096*8
  int cq = gid & 7; int pix = gid >> 3;
  int bb = pix >> 12; int yx = pix & 4095;
  int y = yx >> 6, xx = yx & 63;
  size_t base = (((size_t)bb * 128 + 2 * y) * 128 + 2 * xx) * 64 + cq * 8;
  uint4 va = *(const uint4*)(rbn + base);
  uint4 vb = *(const uint4*)(rbn + base + 64);
  uint4 vc = *(const uint4*)(rbn + base + 8192);
  uint4 vd = *(const uint4*)(rbn + base + 8192 + 64);
  float a[8], b8[8], c8[8], d8[8], o[8];
  unpack8(va, a); unpack8(vb, b8); unpack8(vc, c8); unpack8(vd, d8);
  size_t ob = ((size_t)bb * 4096 + yx) * 1536 + cq * 8;
  #pragma unroll
  for (int j = 0; j < 8; ++j) o[j] = (a[j] + b8[j] + c8[j] + d8[j]) * 0.5f;
  *(uint4*)(cat + ob + 0)   = pack8(o);
  #pragma unroll
  for (int j = 0; j < 8; ++j) o[j] = (a[j] + b8[j] - c8[j] - d8[j]) * 0.5f;
  *(uint4*)(cat + ob + 64)  = pack8(o);
  #pragma unroll
  for (int j = 0; j < 8; ++j) o[j] = (a[j] - b8[j] + c8[j] - d8[j]) * 0.5f;
  *(uint4*)(cat + ob + 128) = pack8(o);
  #pragma unroll
  for (int j = 0; j < 8; ++j) o[j] = (a[j] - b8[j] - c8[j] + d8[j]) * 0.5f;
  *(uint4*)(cat + ob + 192) = pack8(o);
}

// --- unified implicit-GEMM conv (MFMA bf16) --------------------------------
// OUT[b, o, n] = sum_{tap, i} Wt[tap][o][i] * Bf[b][pix(n)+shift(tap)][cbase+i]
// mode 0: bf16 NHWC store (stride OCstr, offset ocbase)
// mode 1: mode 0 + (acc + rb - mean) * g*rsqrt(var+eps) + beta, relu   (M=64)
// mode 2: f32 NCHW store into outf
__global__ __launch_bounds__(256) void k_conv_gemm(
    const unsigned short* __restrict__ Wt, const unsigned short* __restrict__ Bf,
    int M, int Cin, int Cstr, int cbase, int IHW, int lgIW, int KH, int pad,
    unsigned long long wbstride,
    unsigned short* __restrict__ outb, int OCstr, int ocbase,
    float* __restrict__ outf, int mode,
    const float* __restrict__ rb, const float* __restrict__ bng, const float* __restrict__ bnb,
    const float* __restrict__ bnm, const float* __restrict__ bnv) {
  const int tid = threadIdx.x, lane = tid & 63, wid = tid >> 6;
  const int wm = wid >> 1, wn = wid & 1;
  const int bm = blockIdx.y * 128, bn = blockIdx.x * 128;
  const int b = blockIdx.z;
  const int Npix = IHW * IHW;
  if (wbstride) Wt += (size_t)b * wbstride;
  const long long bimg = (long long)b * Npix;

  __shared__ __align__(16) unsigned short sA[128 * 40];
  __shared__ __align__(16) unsigned short sB[128 * 40];

  f32x4 zero4 = {0.f, 0.f, 0.f, 0.f};
  f32x4 acc[4][4];
  #pragma unroll
  for (int i = 0; i < 4; ++i)
    #pragma unroll
    for (int j = 0; j < 4; ++j) acc[i][j] = zero4;

  const int arow = tid >> 2, aslot = tid & 3;
  // staging dest pointers (constant over loop)
  uint4* wA0 = (uint4*)&sA[arow * 40 + aslot * 8];
  uint4* wA1 = (uint4*)&sA[(arow + 64) * 40 + aslot * 8];
  uint4* wB0 = (uint4*)&sB[arow * 40 + aslot * 8];
  uint4* wB1 = (uint4*)&sB[(arow + 64) * 40 + aslot * 8];
  // fragment source pointers (constant over loop)
  const unsigned short* pA[4]; const unsigned short* pB[4];
  #pragma unroll
  for (int mi = 0; mi < 4; ++mi)
    pA[mi] = &sA[(wm * 64 + mi * 16 + (lane & 15)) * 40 + (lane >> 4) * 8];
  #pragma unroll
  for (int ni = 0; ni < 4; ++ni)
    pB[ni] = &sB[(wn * 64 + ni * 16 + (lane & 15)) * 40 + (lane >> 4) * 8];

  const bool am0 = (bm + arow) < M, am1 = (bm + arow + 64) < M;
  const int n0 = bn + arow, n1 = bn + arow + 64;
  const int y0 = n0 >> lgIW, x0 = n0 & (IHW - 1);
  const int y1 = n1 >> lgIW, x1 = n1 & (IHW - 1);
  uint4 z4; z4.x = z4.y = z4.z = z4.w = 0u;

  for (int ty = 0; ty < KH; ++ty) {
    for (int tx = 0; tx < KH; ++tx) {
      const int t = ty * KH + tx;
      const int dy = ty - pad, dx = tx - pad;
      const int ys0 = y0 + dy, xs0 = x0 + dx, ys1 = y1 + dy, xs1 = x1 + dx;
      const bool v0 = ((unsigned)ys0 < (unsigned)IHW) && ((unsigned)xs0 < (unsigned)IHW);
      const bool v1 = ((unsigned)ys1 < (unsigned)IHW) && ((unsigned)xs1 < (unsigned)IHW);
      const unsigned short* bp0 = Bf + (bimg + ys0 * IHW + xs0) * (long long)Cstr + cbase + aslot * 8;
      const unsigned short* bp1 = Bf + (bimg + ys1 * IHW + xs1) * (long long)Cstr + cbase + aslot * 8;
      const unsigned short* ap0 = Wt + ((size_t)t * M + (bm + arow)) * Cin + aslot * 8;
      const unsigned short* ap1 = Wt + ((size_t)t * M + (bm + arow + 64)) * Cin + aslot * 8;
      for (int kc = 0; kc < Cin; kc += 32) {
        uint4 av0 = am0 ? *(const uint4*)(ap0 + kc) : z4;
        uint4 av1 = am1 ? *(const uint4*)(ap1 + kc) : z4;
        uint4 bv0 = v0 ? *(const uint4*)(bp0 + kc) : z4;
        uint4 bv1 = v1 ? *(const uint4*)(bp1 + kc) : z4;
        *wA0 = av0; *wA1 = av1; *wB0 = bv0; *wB1 = bv1;
        __syncthreads();
        bf16x8 af[4], bfr[4];
        #pragma unroll
        for (int mi = 0; mi < 4; ++mi) af[mi] = *(const bf16x8*)pA[mi];
        #pragma unroll
        for (int ni = 0; ni < 4; ++ni) bfr[ni] = *(const bf16x8*)pB[ni];
        #pragma unroll
        for (int mi = 0; mi < 4; ++mi)
          #pragma unroll
          for (int ni = 0; ni < 4; ++ni)
            acc[mi][ni] = __builtin_amdgcn_mfma_f32_16x16x32_bf16(af[mi], bfr[ni], acc[mi][ni], 0, 0, 0);
        __syncthreads();
      }
    }
  }

  // epilogue
  const int mb0 = bm + wm * 64, nb0 = bn + wn * 64;
  #pragma unroll
  for (int mi = 0; mi < 4; ++mi) {
    const int mf = mb0 + mi * 16 + (lane >> 4) * 4;
    if (mf >= M) continue;
    #pragma unroll
    for (int ni = 0; ni < 4; ++ni) {
      const int n = nb0 + ni * 16 + (lane & 15);
      if (mode == 2) {
        #pragma unroll
        for (int vv = 0; vv < 4; ++vv)
          outf[((size_t)b * M + mf + vv) * Npix + n] = acc[mi][ni][vv];
      } else {
        unsigned short h[4];
        #pragma unroll
        for (int vv = 0; vv < 4; ++vv) {
          float val = acc[mi][ni][vv];
          if (mode == 1) {
            int m = mf + vv;
            float scl = bng[m] * rsqrtf(bnv[m] + EPS_);
            val = (val + rb[m] - bnm[m]) * scl + bnb[m];
            val = fmaxf(val, 0.f);
          }
          h[vv] = f2bf(val);
        }
        uint2 st; st.x = (unsigned)h[0] | ((unsigned)h[1] << 16);
        st.y = (unsigned)h[2] | ((unsigned)h[3] << 16);
        *(uint2*)&outb[((size_t)(bimg + n)) * OCstr + ocbase + mf] = st;
      }
    }
  }
}

// --- content conv (256->1) + softmax over 4096 pixels, per batch -----------
__global__ void k_content_softmax(const unsigned short* __restrict__ qkv,
                                  const float* __restrict__ conv_w,
                                  float* __restrict__ content) {
  int b = blockIdx.x, tid = threadIdx.x;
  __shared__ float wl[256];
  __shared__ float red[256];
  wl[tid] = conv_w[tid];
  __syncthreads();
  float sv[16]; float mx = -1e30f;
  #pragma unroll
  for (int j = 0; j < 16; ++j) {
    int p = j * 256 + tid;
    const unsigned short* q = qkv + ((size_t)b * 4096 + p) * 256;
    float s = 0.f;
    for (int i = 0; i < 256; i += 8) {
      uint4 v = *(const uint4*)(q + i);
      float f[8]; unpack8(v, f);
      #pragma unroll
      for (int k = 0; k < 8; ++k) s += f[k] * wl[i + k];
    }
    sv[j] = s; mx = fmaxf(mx, s);
  }
  red[tid] = mx; __syncthreads();
  for (int s = 128; s > 0; s >>= 1) { if (tid < s) red[tid] = fmaxf(red[tid], red[tid + s]); __syncthreads(); }
  mx = red[0]; __syncthreads();
  float sum = 0.f;
  #pragma unroll
  for (int j = 0; j < 16; ++j) { sv[j] = expf(sv[j] - mx); sum += sv[j]; }
  red[tid] = sum; __syncthreads();
  for (int s = 128; s > 0; s >>= 1) { if (tid < s) red[tid] += red[tid + s]; __syncthreads(); }
  float inv = 1.f / red[0];
  #pragma unroll
  for (int j = 0; j < 16; ++j) content[(size_t)b * 4096 + j * 256 + tid] = sv[j] * inv;
}

// --- pooled[b][c] = sum_n chn[b][n][c] * content[b][n] ---------------------
__global__ void k_pooled(const unsigned short* __restrict__ chn,
                         const float* __restrict__ content, float* __restrict__ pooled) {
  int b = blockIdx.x, tid = threadIdx.x;
  const unsigned short* base = chn + (size_t)b * 4096 * 256 + tid;
  const float* ct = content + (size_t)b * 4096;
  float acc = 0.f;
  for (int n = 0; n < 4096; n += 4) {
    acc += bf2f(base[(size_t)(n + 0) * 256]) * ct[n + 0];
    acc += bf2f(base[(size_t)(n + 1) * 256]) * ct[n + 1];
    acc += bf2f(base[(size_t)(n + 2) * 256]) * ct[n + 2];
    acc += bf2f(base[(size_t)(n + 3) * 256]) * ct[n + 3];
  }
  pooled[b * 256 + tid] = acc;
}

// --- ct1 -> LN -> relu -> ct2 : cw[b][256] ---------------------------------
__global__ void k_ct(const float* __restrict__ pooled,
                     const float* __restrict__ ct1w, const float* __restrict__ ct1b,
                     const float* __restrict__ lng, const float* __restrict__ lnb,
                     const float* __restrict__ ct2w, const float* __restrict__ ct2b,
                     float* __restrict__ cw) {
  int b = blockIdx.x, tid = threadIdx.x;
  __shared__ float tt[32];
  __shared__ float stats[2];
  if (tid < 32) {
    float s = 0.f;
    const float* w = ct1w + tid * 256;
    const float* p = pooled + b * 256;
    for (int i = 0; i < 256; ++i) s += w[i] * p[i];
    tt[tid] = s + ct1b[tid];
  }
  __syncthreads();
  if (tid == 0) {
    float mu = 0.f;
    for (int j = 0; j < 32; ++j) mu += tt[j];
    mu *= (1.f / 32.f);
    float va = 0.f;
    for (int j = 0; j < 32; ++j) { float d = tt[j] - mu; va += d * d; }
    va *= (1.f / 32.f);
    stats[0] = mu; stats[1] = rsqrtf(va + EPS_);
  }
  __syncthreads();
  if (tid < 32) {
    float v = (tt[tid] - stats[0]) * stats[1];
    tt[tid] = fmaxf(v * lng[tid] + lnb[tid], 0.f);
  }
  __syncthreads();
  float s = 0.f;
  const float* w2 = ct2w + tid * 32;
  #pragma unroll
  for (int j = 0; j < 32; ++j) s += w2[j] * tt[j];
  cw[b * 256 + tid] = s + ct2b[tid];
}

// --- per-batch proj weights: aproj[b][o][i] = proj_w[o][i]*cw[b][i] --------
__global__ void k_aproj(const float* __restrict__ projw, const float* __restrict__ cw,
                        unsigned short* __restrict__ aproj) {
  int gid = blockIdx.x * 256 + threadIdx.x;   // 16*65536
  int b = gid >> 16; int oi = gid & 65535; int i = oi & 255;
  aproj[gid] = f2bf(projw[oi] * cw[b * 256 + i]);
}

extern "C" void kernel_launch(void* const* d_in, const int* in_sizes, int n_in,
                              void* d_out, int out_size, void* d_ws, size_t ws_size,
                              hipStream_t stream) {
  (void)in_sizes; (void)n_in; (void)out_size; (void)ws_size;
  const float* x        = (const float*)d_in[0];
  const float* reduce_w = (const float*)d_in[1];
  const float* reduce_b = (const float*)d_in[2];
  const float* bn_g     = (const float*)d_in[3];
  const float* bn_b     = (const float*)d_in[4];
  const float* bn_mean  = (const float*)d_in[5];
  const float* bn_var   = (const float*)d_in[6];
  const float* conv_w   = (const float*)d_in[7];
  const float* conv1_w  = (const float*)d_in[8];
  const float* conv2_w  = (const float*)d_in[9];
  const float* conv3_w  = (const float*)d_in[10];
  const float* conv4_w  = (const float*)d_in[11];
  const float* chconv_w = (const float*)d_in[12];
  const float* cat_w    = (const float*)d_in[13];
  const float* ct1_w    = (const float*)d_in[14];
  const float* ct1_b    = (const float*)d_in[15];
  const float* ln_g     = (const float*)d_in[16];
  const float* ln_b     = (const float*)d_in[17];
  const float* ct2_w    = (const float*)d_in[18];
  const float* ct2_b    = (const float*)d_in[19];
  const float* proj_w   = (const float*)d_in[20];

  char* wsp = (char*)d_ws;
  size_t off = 0;
  auto alloc = [&](size_t bytes) -> char* {
    char* p = wsp + off; off += (bytes + 255) & ~(size_t)255; return p;
  };
  unsigned short* XH    = (unsigned short*)alloc((size_t)16 * 16384 * 256 * 2); // 134MB
  unsigned short* CAT   = (unsigned short*)alloc((size_t)16 * 4096 * 1536 * 2); // 201MB
  unsigned short* RBN   = (unsigned short*)alloc((size_t)16 * 16384 * 64 * 2);  // 33.5MB
  unsigned short* QKV   = (unsigned short*)alloc((size_t)16 * 4096 * 256 * 2);  // 33.5MB
  unsigned short* CHN   = (unsigned short*)alloc((size_t)16 * 4096 * 256 * 2);  // 33.5MB
  float*          CONT  = (float*)alloc((size_t)16 * 4096 * 4);
  float*          POOL  = (float*)alloc(16 * 256 * 4);
  float*          CWB   = (float*)alloc(16 * 256 * 4);
  unsigned short* WR    = (unsigned short*)alloc((size_t)64 * 256 * 2);
  unsigned short* W1    = (unsigned short*)alloc((size_t)256 * 256 * 2);
  unsigned short* W2    = (unsigned short*)alloc((size_t)9 * 256 * 256 * 2);
  unsigned short* W3    = (unsigned short*)alloc((size_t)25 * 256 * 256 * 2);
  unsigned short* W4    = (unsigned short*)alloc((size_t)49 * 256 * 256 * 2);
  unsigned short* WC    = (unsigned short*)alloc((size_t)9 * 256 * 256 * 2);
  unsigned short* WCAT  = (unsigned short*)alloc((size_t)9 * 256 * 1536 * 2);
  unsigned short* APROJ = (unsigned short*)alloc((size_t)16 * 256 * 256 * 2);

  auto rp = [&](const float* s, unsigned short* d, int O, int I, int T) {
    int tot = O * I * T;
    k_repack<<<(tot + 255) / 256, 256, 0, stream>>>(s, d, O, I, T);
  };
  rp(reduce_w, WR, 64, 256, 1);
  rp(conv1_w, W1, 256, 256, 1);
  rp(conv2_w, W2, 256, 256, 9);
  rp(conv3_w, W3, 256, 256, 25);
  rp(conv4_w, W4, 256, 256, 49);
  rp(chconv_w, WC, 256, 256, 9);
  rp(cat_w, WCAT, 256, 1536, 9);

  k_transpose_x<<<2048, 256, 0, stream>>>(x, XH);
  k_maxpool<<<8192, 256, 0, stream>>>(XH, CAT);

  dim3 blk(256);
  // reduce conv 1x1 (256->64 @128x128) + BN + relu
  k_conv_gemm<<<dim3(128, 1, 16), blk, 0, stream>>>(WR, XH, 64, 256, 256, 0, 128, 7, 1, 0,
      0ULL, RBN, 64, 0, nullptr, 1, reduce_b, bn_g, bn_b, bn_mean, bn_var);
  k_haar<<<2048, 256, 0, stream>>>(RBN, CAT);
  // branch convs on qkv0 (cat[0:256)) -> cat slices
  k_conv_gemm<<<dim3(32, 2, 16), blk, 0, stream>>>(W1, CAT, 256, 256, 1536, 0, 64, 6, 1, 0,
      0ULL, CAT, 1536, 256, nullptr, 0, nullptr, nullptr, nullptr, nullptr, nullptr);
  k_conv_gemm<<<dim3(32, 2, 16), blk, 0, stream>>>(W2, CAT, 256, 256, 1536, 0, 64, 6, 3, 1,
      0ULL, CAT, 1536, 512, nullptr, 0, nullptr, nullptr, nullptr, nullptr, nullptr);
  k_conv_gemm<<<dim3(32, 2, 16), blk, 0, stream>>>(W3, CAT, 256, 256, 1536, 0, 64, 6, 5, 2,
      0ULL, CAT, 1536, 768, nullptr, 0, nullptr, nullptr, nullptr, nullptr, nullptr);
  k_conv_gemm<<<dim3(32, 2, 16), blk, 0, stream>>>(W4, CAT, 256, 256, 1536, 0, 64, 6, 7, 3,
      0ULL, CAT, 1536, 1024, nullptr, 0, nullptr, nullptr, nullptr, nullptr, nullptr);
  // big conv: 3x3 1536->256 over cat -> qkv
  k_conv_gemm<<<dim3(32, 2, 16), blk, 0, stream>>>(WCAT, CAT, 256, 1536, 1536, 0, 64, 6, 3, 1,
      0ULL, QKV, 256, 0, nullptr, 0, nullptr, nullptr, nullptr, nullptr, nullptr);
  k_content_softmax<<<16, 256, 0, stream>>>(QKV, conv_w, CONT);
  // channel conv: 3x3 256->256 over qkv -> chn
  k_conv_gemm<<<dim3(32, 2, 16), blk, 0, stream>>>(WC, QKV, 256, 256, 256, 0, 64, 6, 3, 1,
      0ULL, CHN, 256, 0, nullptr, 0, nullptr, nullptr, nullptr, nullptr, nullptr);
  k_pooled<<<16, 256, 0, stream>>>(CHN, CONT, POOL);
  k_ct<<<16, 256, 0, stream>>>(POOL, ct1_w, ct1_b, ln_g, ln_b, ct2_w, ct2_b, CWB);
  k_aproj<<<4096, 256, 0, stream>>>(proj_w, CWB, APROJ);
  // proj: per-batch A' = proj_w * cw, 1x1 over qkv -> d_out f32 NCHW
  k_conv_gemm<<<dim3(32, 2, 16), blk, 0, stream>>>(APROJ, QKV, 256, 256, 256, 0, 64, 6, 1, 0,
      65536ULL, nullptr, 256, 0, (float*)d_out, 2, nullptr, nullptr, nullptr, nullptr, nullptr);
}

// Round 2
// 2104.982 us; speedup vs baseline: 1.2384x; 1.2384x over previous
//
#include <hip/hip_runtime.h>
#include <stdint.h>

// ---------------------------------------------------------------------------
// Dwtpool fused pipeline, MI355X gfx950.  Round 2:
//  - conv GEMM moved to m97 structure: global_load_lds width-16 staging,
//    linear [128][32] LDS tiles with k-slot XOR swizzle (conflict-free),
//    zero-padded NHWC feature buffers (no halo branches).
//  - content-softmax / pooled restructured for parallelism.
// ---------------------------------------------------------------------------

typedef __attribute__((ext_vector_type(8))) short bf16x8;
typedef __attribute__((ext_vector_type(4))) float f32x4;

#define EPS_ 1e-5f

#define GLOAD16(gp, lp)                                                        \
  __builtin_amdgcn_global_load_lds(                                            \
      (const __attribute__((address_space(1))) void*)(gp),                     \
      (__attribute__((address_space(3))) void*)(lp), 16, 0, 0)

__device__ __forceinline__ float bf2f(unsigned short u) {
  union { unsigned int u; float f; } c; c.u = ((unsigned int)u) << 16; return c.f;
}
__device__ __forceinline__ unsigned short f2bf(float f) {
  union { float f; unsigned int u; } c; c.f = f;
  return (unsigned short)((c.u + 0x7fffu + ((c.u >> 16) & 1u)) >> 16);
}
__device__ __forceinline__ void unpack8(uint4 v, float* f) {
  f[0]=bf2f((unsigned short)(v.x&0xffffu)); f[1]=bf2f((unsigned short)(v.x>>16));
  f[2]=bf2f((unsigned short)(v.y&0xffffu)); f[3]=bf2f((unsigned short)(v.y>>16));
  f[4]=bf2f((unsigned short)(v.z&0xffffu)); f[5]=bf2f((unsigned short)(v.z>>16));
  f[6]=bf2f((unsigned short)(v.w&0xffffu)); f[7]=bf2f((unsigned short)(v.w>>16));
}
__device__ __forceinline__ uint4 pack8(const float* f) {
  uint4 v;
  v.x = (unsigned)f2bf(f[0]) | ((unsigned)f2bf(f[1])<<16);
  v.y = (unsigned)f2bf(f[2]) | ((unsigned)f2bf(f[3])<<16);
  v.z = (unsigned)f2bf(f[4]) | ((unsigned)f2bf(f[5])<<16);
  v.w = (unsigned)f2bf(f[6]) | ((unsigned)f2bf(f[7])<<16);
  return v;
}

// --- weight repack: OIHW f32 -> [tap][Opad][I] bf16 (zero rows O..Opad) ----
__global__ void k_repack(const float* __restrict__ src, unsigned short* __restrict__ dst,
                         int O, int Opad, int I, int T) {
  int gid = blockIdx.x * 256 + threadIdx.x;
  if (gid >= Opad * I * T) return;
  int i = gid % I; int r = gid / I; int o = r % Opad; int t = r / Opad;
  dst[gid] = (o < O) ? f2bf(src[((size_t)(o * I + i)) * T + t]) : (unsigned short)0;
}

// --- zero border ring of a padded NHWC buffer (16 batches) -----------------
__global__ void k_border_zero(unsigned short* __restrict__ buf, int PW, int PB, int C) {
  int IW = PW - 2 * PB;
  int nb = PW * PW - IW * IW;
  int per = C >> 3;
  int gid = blockIdx.x * 256 + threadIdx.x;
  if (gid >= 16 * nb * per) return;
  int cq = gid % per; int r = gid / per; int p = r % nb; int b = r / nb;
  int y, x;
  int top = PB * PW;
  if (p < top) { y = p / PW; x = p - y * PW; }
  else if (p < top + IW * 2 * PB) {
    int q = p - top; y = PB + q / (2 * PB); int rr = q % (2 * PB);
    x = (rr < PB) ? rr : (IW + rr);
  } else { int q = p - top - IW * 2 * PB; y = PB + IW + q / PW; x = q - (q / PW) * PW; }
  uint4 z; z.x = z.y = z.z = z.w = 0u;
  *(uint4*)&buf[(((size_t)b * PW + y) * PW + x) * C + cq * 8] = z;
}

// --- x: NCHW f32 -> NHWC bf16 [16][128][128][256] --------------------------
__global__ void k_transpose_x(const float* __restrict__ x, unsigned short* __restrict__ xh) {
  int by = blockIdx.x; int b = by >> 7; int y = by & 127;
  int tid = threadIdx.x;
  __shared__ unsigned short lds[32 * 129];
  for (int c0 = 0; c0 < 256; c0 += 32) {
    #pragma unroll
    for (int i = 0; i < 16; ++i) {
      int e = i * 256 + tid; int ci = e >> 7, xx = e & 127;
      float v = x[(((size_t)b * 256 + c0 + ci) * 128 + y) * 128 + xx];
      lds[ci * 129 + xx] = f2bf(v);
    }
    __syncthreads();
    #pragma unroll
    for (int i2 = 0; i2 < 2; ++i2) {
      int e = i2 * 256 + tid; int pix = e >> 2, q = e & 3;
      unsigned int w0, w1, w2, w3;
      w0 = (unsigned)lds[(q*8+0)*129 + pix] | ((unsigned)lds[(q*8+1)*129 + pix] << 16);
      w1 = (unsigned)lds[(q*8+2)*129 + pix] | ((unsigned)lds[(q*8+3)*129 + pix] << 16);
      w2 = (unsigned)lds[(q*8+4)*129 + pix] | ((unsigned)lds[(q*8+5)*129 + pix] << 16);
      w3 = (unsigned)lds[(q*8+6)*129 + pix] | ((unsigned)lds[(q*8+7)*129 + pix] << 16);
      uint4 v; v.x = w0; v.y = w1; v.z = w2; v.w = w3;
      *(uint4*)&xh[(((size_t)b * 128 + y) * 128 + pix) * 256 + c0 + q * 8] = v;
    }
    __syncthreads();
  }
}

// --- maxpool 2x2 on xh -> CAT(padded 70x70) channels [1280..1536) ----------
__global__ void k_maxpool(const unsigned short* __restrict__ xh, unsigned short* __restrict__ cat) {
  int gid = blockIdx.x * 256 + threadIdx.x;        // 16*4096*32
  int cq = gid & 31; int pix = gid >> 5;
  int bb = pix >> 12; int yx = pix & 4095;
  int y = yx >> 6, xx2 = yx & 63;
  size_t base = (((size_t)bb * 128 + 2 * y) * 128 + 2 * xx2) * 256 + cq * 8;
  uint4 v00 = *(const uint4*)(xh + base);
  uint4 v01 = *(const uint4*)(xh + base + 256);
  uint4 v10 = *(const uint4*)(xh + base + 32768);
  uint4 v11 = *(const uint4*)(xh + base + 32768 + 256);
  float a[8], b8[8], c8[8], d8[8], m8[8];
  unpack8(v00, a); unpack8(v01, b8); unpack8(v10, c8); unpack8(v11, d8);
  #pragma unroll
  for (int j = 0; j < 8; ++j) m8[j] = fmaxf(fmaxf(a[j], b8[j]), fmaxf(c8[j], d8[j]));
  *(uint4*)(cat + (((size_t)bb * 4900 + (y + 3) * 70 + (xx2 + 3))) * 1536 + 1280 + cq * 8) = pack8(m8);
}

// --- haar DWT: rbn [16][128][128][64] -> CAT(padded) channels [0..256) -----
__global__ void k_haar(const unsigned short* __restrict__ rbn, unsigned short* __restrict__ cat) {
  int gid = blockIdx.x * 256 + threadIdx.x;        // 16*4096*8
  int cq = gid & 7; int pix = gid >> 3;
  int bb = pix >> 12; int yx = pix & 4095;
  int y = yx >> 6, xx = yx & 63;
  size_t base = (((size_t)bb * 128 + 2 * y) * 128 + 2 * xx) * 64 + cq * 8;
  uint4 va = *(const uint4*)(rbn + base);
  uint4 vb = *(const uint4*)(rbn + base + 64);
  uint4 vc = *(const uint4*)(rbn + base + 8192);
  uint4 vd = *(const uint4*)(rbn + base + 8192 + 64);
  float a[8], b8[8], c8[8], d8[8], o[8];
  unpack8(va, a); unpack8(vb, b8); unpack8(vc, c8); unpack8(vd, d8);
  size_t ob = ((size_t)bb * 4900 + (y + 3) * 70 + (xx + 3)) * 1536 + cq * 8;
  #pragma unroll
  for (int j = 0; j < 8; ++j) o[j] = (a[j] + b8[j] + c8[j] + d8[j]) * 0.5f;
  *(uint4*)(cat + ob + 0)   = pack8(o);
  #pragma unroll
  for (int j = 0; j < 8; ++j) o[j] = (a[j] + b8[j] - c8[j] - d8[j]) * 0.5f;
  *(uint4*)(cat + ob + 64)  = pack8(o);
  #pragma unroll
  for (int j = 0; j < 8; ++j) o[j] = (a[j] - b8[j] + c8[j] - d8[j]) * 0.5f;
  *(uint4*)(cat + ob + 128) = pack8(o);
  #pragma unroll
  for (int j = 0; j < 8; ++j) o[j] = (a[j] - b8[j] - c8[j] + d8[j]) * 0.5f;
  *(uint4*)(cat + ob + 192) = pack8(o);
}

// --- unified implicit-GEMM conv (MFMA bf16, global_load_lds staging) -------
// B buffer is zero-padded NHWC: pixel (y,x) of the OW x OW interior lives at
// buffer pixel (y+PB, x+PB) of a PW x PW image; PB >= conv pad, so all tap
// reads are in-bounds (borders zero).  LDS tiles are linear [128][32] bf16
// with k-slot XOR swizzle s^=(row>>1)&3 applied on the per-lane GLOBAL source
// address and on the ds_read fragment address (cancels -> canonical MFMA k).
__global__ __launch_bounds__(256) void k_conv_gemm(
    const unsigned short* __restrict__ Wt, const unsigned short* __restrict__ Bf,
    int M, int Mpad, int Cin, int Cstr, int cbase,
    int OW, int lgOW, int PW, int PB, int KH, int pad,
    unsigned long long wbstride,
    unsigned short* __restrict__ outb, int OCstr, int ocbase, int OPW, int OPB,
    float* __restrict__ outf, int mode,
    const float* __restrict__ rb, const float* __restrict__ bng, const float* __restrict__ bnb,
    const float* __restrict__ bnm, const float* __restrict__ bnv) {
  const int tid = threadIdx.x, lane = tid & 63, w = tid >> 6;
  const int wm = w >> 1, wn = w & 1;
  const int bm = blockIdx.y * 128, bn = blockIdx.x * 128;
  const int b = blockIdx.z;
  const int Npix = OW * OW;
  if (wbstride) Wt += (size_t)b * wbstride;

  __shared__ __align__(1024) unsigned short sA[128 * 32];
  __shared__ __align__(1024) unsigned short sB[128 * 32];

  f32x4 zero4 = {0.f, 0.f, 0.f, 0.f};
  f32x4 acc[4][4];
  #pragma unroll
  for (int i = 0; i < 4; ++i)
    #pragma unroll
    for (int j = 0; j < 4; ++j) acc[i][j] = zero4;

  // --- staging lane decomposition (16 rows x 4 slots per gload instr) ---
  const int srow = lane >> 2;                 // 0..15
  const int slog = (lane & 3) ^ ((lane >> 3) & 3);  // swizzled k-slot
  const int r0 = w * 32;                      // wave's row base in tile
  // A source rows
  const unsigned short* aRow = Wt + ((size_t)(bm + r0 + srow)) * Cin + slog * 8;
  // B source rows (pixels)
  const int n0 = bn + r0 + srow, n1 = n0 + 16;
  const int y0 = n0 >> lgOW, x0 = n0 & (OW - 1);
  const int y1 = n1 >> lgOW, x1 = n1 & (OW - 1);
  const size_t bimg = (size_t)b * PW * PW;
  const unsigned short* bRow0 = Bf + (bimg + (size_t)(y0 + PB) * PW + (x0 + PB)) * Cstr + cbase + slog * 8;
  const unsigned short* bRow1 = Bf + (bimg + (size_t)(y1 + PB) * PW + (x1 + PB)) * Cstr + cbase + slog * 8;
  // LDS dest bases (wave-uniform, linear)
  unsigned short* ldsA0 = &sA[(r0) * 32];
  unsigned short* ldsA1 = &sA[(r0 + 16) * 32];
  unsigned short* ldsB0 = &sB[(r0) * 32];
  unsigned short* ldsB1 = &sB[(r0 + 16) * 32];

  // --- fragment read pointers (swizzled, constant over loop) ---
  const int rowfrag = lane & 15, hi = lane >> 4;
  const int sl = hi ^ ((rowfrag >> 1) & 3);
  const bf16x8* pA[4]; const bf16x8* pB[4];
  #pragma unroll
  for (int mi = 0; mi < 4; ++mi)
    pA[mi] = (const bf16x8*)&sA[(wm * 64 + mi * 16 + rowfrag) * 32 + sl * 8];
  #pragma unroll
  for (int ni = 0; ni < 4; ++ni)
    pB[ni] = (const bf16x8*)&sB[(wn * 64 + ni * 16 + rowfrag) * 32 + sl * 8];

  const size_t MC = (size_t)Mpad * Cin;
  for (int ty = 0; ty < KH; ++ty) {
    for (int tx = 0; tx < KH; ++tx) {
      const unsigned short* at = aRow + (size_t)(ty * KH + tx) * MC;
      const long long toff = ((long long)(ty - pad) * PW + (tx - pad)) * Cstr;
      const unsigned short* bt0 = bRow0 + toff;
      const unsigned short* bt1 = bRow1 + toff;
      for (int kc = 0; kc < Cin; kc += 32) {
        GLOAD16(at + kc, ldsA0);
        GLOAD16(at + (size_t)16 * Cin + kc, ldsA1);
        GLOAD16(bt0 + kc, ldsB0);
        GLOAD16(bt1 + kc, ldsB1);
        __syncthreads();
        bf16x8 af[4], bfr[4];
        #pragma unroll
        for (int mi = 0; mi < 4; ++mi) af[mi] = *pA[mi];
        #pragma unroll
        for (int ni = 0; ni < 4; ++ni) bfr[ni] = *pB[ni];
        #pragma unroll
        for (int mi = 0; mi < 4; ++mi)
          #pragma unroll
          for (int ni = 0; ni < 4; ++ni)
            acc[mi][ni] = __builtin_amdgcn_mfma_f32_16x16x32_bf16(af[mi], bfr[ni], acc[mi][ni], 0, 0, 0);
        __syncthreads();
      }
    }
  }

  // epilogue
  const int mb0 = bm + wm * 64, nb0 = bn + wn * 64;
  const size_t bimgO = (size_t)b * OPW * OPW;
  #pragma unroll
  for (int mi = 0; mi < 4; ++mi) {
    const int mf = mb0 + mi * 16 + (lane >> 4) * 4;
    if (mf >= M) continue;
    #pragma unroll
    for (int ni = 0; ni < 4; ++ni) {
      const int n = nb0 + ni * 16 + (lane & 15);
      if (mode == 2) {
        #pragma unroll
        for (int vv = 0; vv < 4; ++vv)
          outf[((size_t)b * M + mf + vv) * Npix + n] = acc[mi][ni][vv];
      } else {
        const int oy = n >> lgOW, ox = n & (OW - 1);
        unsigned short h[4];
        #pragma unroll
        for (int vv = 0; vv < 4; ++vv) {
          float val = acc[mi][ni][vv];
          if (mode == 1) {
            int m = mf + vv;
            float scl = bng[m] * rsqrtf(bnv[m] + EPS_);
            val = (val + rb[m] - bnm[m]) * scl + bnb[m];
            val = fmaxf(val, 0.f);
          }
          h[vv] = f2bf(val);
        }
        uint2 st; st.x = (unsigned)h[0] | ((unsigned)h[1] << 16);
        st.y = (unsigned)h[2] | ((unsigned)h[3] << 16);
        *(uint2*)&outb[(bimgO + (size_t)(oy + OPB) * OPW + (ox + OPB)) * OCstr + ocbase + mf] = st;
      }
    }
  }
}

// --- content logits: dot(qkv[pix], w) over 256 ch, 512 blocks --------------
__global__ void k_content_logits(const unsigned short* __restrict__ qkv,
                                 const float* __restrict__ conv_w,
                                 float* __restrict__ logits) {
  int j = blockIdx.x, b = blockIdx.y, tid = threadIdx.x;
  __shared__ float wl[256];
  wl[tid] = conv_w[tid];
  __syncthreads();
  int pl = tid >> 3, kp = tid & 7;
  #pragma unroll
  for (int pass = 0; pass < 4; ++pass) {
    int p = j * 128 + pass * 32 + pl;
    int y = p >> 6, x = p & 63;
    const unsigned short* q = qkv + (((size_t)b * 66 + y + 1) * 66 + (x + 1)) * 256 + kp * 32;
    float s = 0.f;
    #pragma unroll
    for (int i = 0; i < 32; i += 8) {
      uint4 v = *(const uint4*)(q + i);
      float f[8]; unpack8(v, f);
      #pragma unroll
      for (int k = 0; k < 8; ++k) s += f[k] * wl[kp * 32 + i + k];
    }
    s += __shfl_down(s, 4, 8);
    s += __shfl_down(s, 2, 8);
    s += __shfl_down(s, 1, 8);
    if (kp == 0) logits[(size_t)b * 4096 + p] = s;
  }
}

// --- softmax over 4096 per batch (in place on logits) ----------------------
__global__ void k_softmax4096(float* __restrict__ cont) {
  int b = blockIdx.x, tid = threadIdx.x;
  __shared__ float red[256];
  float sv[16]; float mx = -1e30f;
  #pragma unroll
  for (int j = 0; j < 16; ++j) { sv[j] = cont[(size_t)b * 4096 + j * 256 + tid]; mx = fmaxf(mx, sv[j]); }
  red[tid] = mx; __syncthreads();
  for (int s = 128; s > 0; s >>= 1) { if (tid < s) red[tid] = fmaxf(red[tid], red[tid + s]); __syncthreads(); }
  mx = red[0]; __syncthreads();
  float sum = 0.f;
  #pragma unroll
  for (int j = 0; j < 16; ++j) { sv[j] = expf(sv[j] - mx); sum += sv[j]; }
  red[tid] = sum; __syncthreads();
  for (int s = 128; s > 0; s >>= 1) { if (tid < s) red[tid] += red[tid + s]; __syncthreads(); }
  float inv = 1.f / red[0];
  #pragma unroll
  for (int j = 0; j < 16; ++j) cont[(size_t)b * 4096 + j * 256 + tid] = sv[j] * inv;
}

// --- pooled partials: 32 chunks of 128 pixels per batch --------------------
__global__ void k_pooled_part(const unsigned short* __restrict__ chn,
                              const float* __restrict__ content, float* __restrict__ ppart) {
  int j = blockIdx.x, b = blockIdx.y, c = threadIdx.x;
  const unsigned short* base = chn + (size_t)b * 4096 * 256 + c;
  const float* ct = content + (size_t)b * 4096;
  float acc = 0.f;
  int n0 = j * 128;
  for (int n = n0; n < n0 + 128; ++n)
    acc += bf2f(base[(size_t)n * 256]) * ct[n];
  ppart[((size_t)b * 32 + j) * 256 + c] = acc;
}
__global__ void k_pooled_red(const float* __restrict__ ppart, float* __restrict__ pooled) {
  int b = blockIdx.x, c = threadIdx.x;
  float s = 0.f;
  #pragma unroll
  for (int j = 0; j < 32; ++j) s += ppart[((size_t)b * 32 + j) * 256 + c];
  pooled[b * 256 + c] = s;
}

// --- ct1 -> LN -> relu -> ct2 : cw[b][256] ---------------------------------
__global__ void k_ct(const float* __restrict__ pooled,
                     const float* __restrict__ ct1w, const float* __restrict__ ct1b,
                     const float* __restrict__ lng, const float* __restrict__ lnb,
                     const float* __restrict__ ct2w, const float* __restrict__ ct2b,
                     float* __restrict__ cw) {
  int b = blockIdx.x, tid = threadIdx.x;
  __shared__ float tt[32];
  __shared__ float stats[2];
  if (tid < 32) {
    float s = 0.f;
    const float* w = ct1w + tid * 256;
    const float* p = pooled + b * 256;
    for (int i = 0; i < 256; ++i) s += w[i] * p[i];
    tt[tid] = s + ct1b[tid];
  }
  __syncthreads();
  if (tid == 0) {
    float mu = 0.f;
    for (int j = 0; j < 32; ++j) mu += tt[j];
    mu *= (1.f / 32.f);
    float va = 0.f;
    for (int j = 0; j < 32; ++j) { float d = tt[j] - mu; va += d * d; }
    va *= (1.f / 32.f);
    stats[0] = mu; stats[1] = rsqrtf(va + EPS_);
  }
  __syncthreads();
  if (tid < 32) {
    float v = (tt[tid] - stats[0]) * stats[1];
    tt[tid] = fmaxf(v * lng[tid] + lnb[tid], 0.f);
  }
  __syncthreads();
  float s = 0.f;
  const float* w2 = ct2w + tid * 32;
  #pragma unroll
  for (int j = 0; j < 32; ++j) s += w2[j] * tt[j];
  cw[b * 256 + tid] = s + ct2b[tid];
}

// --- per-batch proj weights: aproj[b][o][i] = proj_w[o][i]*cw[b][i] --------
__global__ void k_aproj(const float* __restrict__ projw, const float* __restrict__ cw,
                        unsigned short* __restrict__ aproj) {
  int gid = blockIdx.x * 256 + threadIdx.x;   // 16*65536
  int b = gid >> 16; int oi = gid & 65535; int i = oi & 255;
  aproj[gid] = f2bf(projw[oi] * cw[b * 256 + i]);
}

extern "C" void kernel_launch(void* const* d_in, const int* in_sizes, int n_in,
                              void* d_out, int out_size, void* d_ws, size_t ws_size,
                              hipStream_t stream) {
  (void)in_sizes; (void)n_in; (void)out_size; (void)ws_size;
  const float* x        = (const float*)d_in[0];
  const float* reduce_w = (const float*)d_in[1];
  const float* reduce_b = (const float*)d_in[2];
  const float* bn_g     = (const float*)d_in[3];
  const float* bn_b     = (const float*)d_in[4];
  const float* bn_mean  = (const float*)d_in[5];
  const float* bn_var   = (const float*)d_in[6];
  const float* conv_w   = (const float*)d_in[7];
  const float* conv1_w  = (const float*)d_in[8];
  const float* conv2_w  = (const float*)d_in[9];
  const float* conv3_w  = (const float*)d_in[10];
  const float* conv4_w  = (const float*)d_in[11];
  const float* chconv_w = (const float*)d_in[12];
  const float* cat_w    = (const float*)d_in[13];
  const float* ct1_w    = (const float*)d_in[14];
  const float* ct1_b    = (const float*)d_in[15];
  const float* ln_g     = (const float*)d_in[16];
  const float* ln_b     = (const float*)d_in[17];
  const float* ct2_w    = (const float*)d_in[18];
  const float* ct2_b    = (const float*)d_in[19];
  const float* proj_w   = (const float*)d_in[20];

  char* wsp = (char*)d_ws;
  size_t off = 0;
  auto alloc = [&](size_t bytes) -> char* {
    char* p = wsp + off; off += (bytes + 255) & ~(size_t)255; return p;
  };
  unsigned short* XH    = (unsigned short*)alloc((size_t)16 * 16384 * 256 * 2); // 134MB
  unsigned short* CAT   = (unsigned short*)alloc((size_t)16 * 4900 * 1536 * 2); // 241MB (70x70 pad3)
  unsigned short* RBN   = (unsigned short*)alloc((size_t)16 * 16384 * 64 * 2);  // 33.5MB (aliased as CHN)
  unsigned short* CHN   = RBN;  // disjoint lifetimes: RBN dies after haar
  unsigned short* QKV   = (unsigned short*)alloc((size_t)16 * 4356 * 256 * 2);  // 35.7MB (66x66 pad1)
  float*          CONT  = (float*)alloc((size_t)16 * 4096 * 4);
  float*          PPART = (float*)alloc((size_t)16 * 32 * 256 * 4);
  float*          POOL  = (float*)alloc(16 * 256 * 4);
  float*          CWB   = (float*)alloc(16 * 256 * 4);
  unsigned short* WR    = (unsigned short*)alloc((size_t)128 * 256 * 2);
  unsigned short* W1    = (unsigned short*)alloc((size_t)256 * 256 * 2);
  unsigned short* W2    = (unsigned short*)alloc((size_t)9 * 256 * 256 * 2);
  unsigned short* W3    = (unsigned short*)alloc((size_t)25 * 256 * 256 * 2);
  unsigned short* W4    = (unsigned short*)alloc((size_t)49 * 256 * 256 * 2);
  unsigned short* WC    = (unsigned short*)alloc((size_t)9 * 256 * 256 * 2);
  unsigned short* WCAT  = (unsigned short*)alloc((size_t)9 * 256 * 1536 * 2);
  unsigned short* APROJ = (unsigned short*)alloc((size_t)16 * 256 * 256 * 2);

  auto rp = [&](const float* s, unsigned short* d, int O, int Opad, int I, int T) {
    int tot = Opad * I * T;
    k_repack<<<(tot + 255) / 256, 256, 0, stream>>>(s, d, O, Opad, I, T);
  };
  rp(reduce_w, WR, 64, 128, 256, 1);
  rp(conv1_w, W1, 256, 256, 256, 1);
  rp(conv2_w, W2, 256, 256, 256, 9);
  rp(conv3_w, W3, 256, 256, 256, 25);
  rp(conv4_w, W4, 256, 256, 256, 49);
  rp(chconv_w, WC, 256, 256, 256, 9);
  rp(cat_w, WCAT, 256, 256, 1536, 9);

  // zero padded borders (CAT: 70x70 pad3 x1536ch; QKV: 66x66 pad1 x256ch)
  k_border_zero<<<(16 * 804 * 192 + 255) / 256, 256, 0, stream>>>(CAT, 70, 3, 1536);
  k_border_zero<<<(16 * 260 * 32 + 255) / 256, 256, 0, stream>>>(QKV, 66, 1, 256);

  k_transpose_x<<<2048, 256, 0, stream>>>(x, XH);
  k_maxpool<<<8192, 256, 0, stream>>>(XH, CAT);

  dim3 blk(256);
  // reduce conv 1x1 (256->64 @128x128, Mpad=128) + BN + relu -> RBN
  k_conv_gemm<<<dim3(128, 1, 16), blk, 0, stream>>>(WR, XH, 64, 128, 256, 256, 0,
      128, 7, 128, 0, 1, 0, 0ULL, RBN, 64, 0, 128, 0, nullptr, 1,
      reduce_b, bn_g, bn_b, bn_mean, bn_var);
  k_haar<<<2048, 256, 0, stream>>>(RBN, CAT);
  // branch convs on qkv0 (CAT ch[0:256)) -> CAT slices
  k_conv_gemm<<<dim3(32, 2, 16), blk, 0, stream>>>(W1, CAT, 256, 256, 256, 1536, 0,
      64, 6, 70, 3, 1, 0, 0ULL, CAT, 1536, 256, 70, 3, nullptr, 0,
      nullptr, nullptr, nullptr, nullptr, nullptr);
  k_conv_gemm<<<dim3(32, 2, 16), blk, 0, stream>>>(W2, CAT, 256, 256, 256, 1536, 0,
      64, 6, 70, 3, 3, 1, 0ULL, CAT, 1536, 512, 70, 3, nullptr, 0,
      nullptr, nullptr, nullptr, nullptr, nullptr);
  k_conv_gemm<<<dim3(32, 2, 16), blk, 0, stream>>>(W3, CAT, 256, 256, 256, 1536, 0,
      64, 6, 70, 3, 5, 2, 0ULL, CAT, 1536, 768, 70, 3, nullptr, 0,
      nullptr, nullptr, nullptr, nullptr, nullptr);
  k_conv_gemm<<<dim3(32, 2, 16), blk, 0, stream>>>(W4, CAT, 256, 256, 256, 1536, 0,
      64, 6, 70, 3, 7, 3, 0ULL, CAT, 1536, 1024, 70, 3, nullptr, 0,
      nullptr, nullptr, nullptr, nullptr, nullptr);
  // big conv: 3x3 1536->256 over CAT -> QKV (padded 66x66)
  k_conv_gemm<<<dim3(32, 2, 16), blk, 0, stream>>>(WCAT, CAT, 256, 256, 1536, 1536, 0,
      64, 6, 70, 3, 3, 1, 0ULL, QKV, 256, 0, 66, 1, nullptr, 0,
      nullptr, nullptr, nullptr, nullptr, nullptr);
  k_content_logits<<<dim3(32, 16), blk, 0, stream>>>(QKV, conv_w, CONT);
  k_softmax4096<<<16, blk, 0, stream>>>(CONT);
  // channel conv: 3x3 256->256 over QKV -> CHN (unpadded)
  k_conv_gemm<<<dim3(32, 2, 16), blk, 0, stream>>>(WC, QKV, 256, 256, 256, 256, 0,
      64, 6, 66, 1, 3, 1, 0ULL, CHN, 256, 0, 64, 0, nullptr, 0,
      nullptr, nullptr, nullptr, nullptr, nullptr);
  k_pooled_part<<<dim3(32, 16), blk, 0, stream>>>(CHN, CONT, PPART);
  k_pooled_red<<<16, blk, 0, stream>>>(PPART, POOL);
  k_ct<<<16, blk, 0, stream>>>(POOL, ct1_w, ct1_b, ln_g, ln_b, ct2_w, ct2_b, CWB);
  k_aproj<<<4096, 256, 0, stream>>>(proj_w, CWB, APROJ);
  // proj: per-batch A' = proj_w * cw, 1x1 over QKV -> d_out f32 NCHW
  k_conv_gemm<<<dim3(32, 2, 16), blk, 0, stream>>>(APROJ, QKV, 256, 256, 256, 256, 0,
      64, 6, 66, 1, 1, 0, 65536ULL, nullptr, 256, 0, 64, 0, (float*)d_out, 2,
      nullptr, nullptr, nullptr, nullptr, nullptr);
}

// Round 3
// 1450.933 us; speedup vs baseline: 1.7966x; 1.4508x over previous
//
#include <hip/hip_runtime.h>
#include <stdint.h>

// ---------------------------------------------------------------------------
// Dwtpool fused pipeline, MI355X gfx950.  Round 3:
//  - NEW k_conv_gemm256: 256x256 tile, BK=64, 8 waves, 128KB LDS dbuf,
//    4-phase schedule per K-tile (ds_read || front-loaded gload_lds -> barrier
//    -> 16 MFMA -> barrier), vmcnt(0) once per K-tile, setprio on MFMA.
//  - chunk-rotation LDS swizzle (2-way = free), flattened tap pipeline.
//  - 128^2 kernel retained for the M=64 reduce conv.
// ---------------------------------------------------------------------------

typedef __attribute__((ext_vector_type(8))) short bf16x8;
typedef __attribute__((ext_vector_type(4))) float f32x4;

#define EPS_ 1e-5f

#define GLOAD16(gp, lp)                                                        \
  __builtin_amdgcn_global_load_lds(                                            \
      (const __attribute__((address_space(1))) void*)(gp),                     \
      (__attribute__((address_space(3))) void*)(lp), 16, 0, 0)

__device__ __forceinline__ float bf2f(unsigned short u) {
  union { unsigned int u; float f; } c; c.u = ((unsigned int)u) << 16; return c.f;
}
__device__ __forceinline__ unsigned short f2bf(float f) {
  union { float f; unsigned int u; } c; c.f = f;
  return (unsigned short)((c.u + 0x7fffu + ((c.u >> 16) & 1u)) >> 16);
}
__device__ __forceinline__ void unpack8(uint4 v, float* f) {
  f[0]=bf2f((unsigned short)(v.x&0xffffu)); f[1]=bf2f((unsigned short)(v.x>>16));
  f[2]=bf2f((unsigned short)(v.y&0xffffu)); f[3]=bf2f((unsigned short)(v.y>>16));
  f[4]=bf2f((unsigned short)(v.z&0xffffu)); f[5]=bf2f((unsigned short)(v.z>>16));
  f[6]=bf2f((unsigned short)(v.w&0xffffu)); f[7]=bf2f((unsigned short)(v.w>>16));
}
__device__ __forceinline__ uint4 pack8(const float* f) {
  uint4 v;
  v.x = (unsigned)f2bf(f[0]) | ((unsigned)f2bf(f[1])<<16);
  v.y = (unsigned)f2bf(f[2]) | ((unsigned)f2bf(f[3])<<16);
  v.z = (unsigned)f2bf(f[4]) | ((unsigned)f2bf(f[5])<<16);
  v.w = (unsigned)f2bf(f[6]) | ((unsigned)f2bf(f[7])<<16);
  return v;
}

// --- weight repack: OIHW f32 -> [tap][Opad][I] bf16 (zero rows O..Opad) ----
__global__ void k_repack(const float* __restrict__ src, unsigned short* __restrict__ dst,
                         int O, int Opad, int I, int T) {
  int gid = blockIdx.x * 256 + threadIdx.x;
  if (gid >= Opad * I * T) return;
  int i = gid % I; int r = gid / I; int o = r % Opad; int t = r / Opad;
  dst[gid] = (o < O) ? f2bf(src[((size_t)(o * I + i)) * T + t]) : (unsigned short)0;
}

// --- zero border ring of a padded NHWC buffer (16 batches) -----------------
__global__ void k_border_zero(unsigned short* __restrict__ buf, int PW, int PB, int C) {
  int IW = PW - 2 * PB;
  int nb = PW * PW - IW * IW;
  int per = C >> 3;
  int gid = blockIdx.x * 256 + threadIdx.x;
  if (gid >= 16 * nb * per) return;
  int cq = gid % per; int r = gid / per; int p = r % nb; int b = r / nb;
  int y, x;
  int top = PB * PW;
  if (p < top) { y = p / PW; x = p - y * PW; }
  else if (p < top + IW * 2 * PB) {
    int q = p - top; y = PB + q / (2 * PB); int rr = q % (2 * PB);
    x = (rr < PB) ? rr : (IW + rr);
  } else { int q = p - top - IW * 2 * PB; y = PB + IW + q / PW; x = q - (q / PW) * PW; }
  uint4 z; z.x = z.y = z.z = z.w = 0u;
  *(uint4*)&buf[(((size_t)b * PW + y) * PW + x) * C + cq * 8] = z;
}

// --- x: NCHW f32 -> NHWC bf16 [16][128][128][256] --------------------------
__global__ void k_transpose_x(const float* __restrict__ x, unsigned short* __restrict__ xh) {
  int by = blockIdx.x; int b = by >> 7; int y = by & 127;
  int tid = threadIdx.x;
  __shared__ unsigned short lds[32 * 129];
  for (int c0 = 0; c0 < 256; c0 += 32) {
    #pragma unroll
    for (int i = 0; i < 16; ++i) {
      int e = i * 256 + tid; int ci = e >> 7, xx = e & 127;
      float v = x[(((size_t)b * 256 + c0 + ci) * 128 + y) * 128 + xx];
      lds[ci * 129 + xx] = f2bf(v);
    }
    __syncthreads();
    #pragma unroll
    for (int i2 = 0; i2 < 2; ++i2) {
      int e = i2 * 256 + tid; int pix = e >> 2, q = e & 3;
      unsigned int w0, w1, w2, w3;
      w0 = (unsigned)lds[(q*8+0)*129 + pix] | ((unsigned)lds[(q*8+1)*129 + pix] << 16);
      w1 = (unsigned)lds[(q*8+2)*129 + pix] | ((unsigned)lds[(q*8+3)*129 + pix] << 16);
      w2 = (unsigned)lds[(q*8+4)*129 + pix] | ((unsigned)lds[(q*8+5)*129 + pix] << 16);
      w3 = (unsigned)lds[(q*8+6)*129 + pix] | ((unsigned)lds[(q*8+7)*129 + pix] << 16);
      uint4 v; v.x = w0; v.y = w1; v.z = w2; v.w = w3;
      *(uint4*)&xh[(((size_t)b * 128 + y) * 128 + pix) * 256 + c0 + q * 8] = v;
    }
    __syncthreads();
  }
}

// --- maxpool 2x2 on xh -> CAT(padded 70x70) channels [1280..1536) ----------
__global__ void k_maxpool(const unsigned short* __restrict__ xh, unsigned short* __restrict__ cat) {
  int gid = blockIdx.x * 256 + threadIdx.x;        // 16*4096*32
  int cq = gid & 31; int pix = gid >> 5;
  int bb = pix >> 12; int yx = pix & 4095;
  int y = yx >> 6, xx2 = yx & 63;
  size_t base = (((size_t)bb * 128 + 2 * y) * 128 + 2 * xx2) * 256 + cq * 8;
  uint4 v00 = *(const uint4*)(xh + base);
  uint4 v01 = *(const uint4*)(xh + base + 256);
  uint4 v10 = *(const uint4*)(xh + base + 32768);
  uint4 v11 = *(const uint4*)(xh + base + 32768 + 256);
  float a[8], b8[8], c8[8], d8[8], m8[8];
  unpack8(v00, a); unpack8(v01, b8); unpack8(v10, c8); unpack8(v11, d8);
  #pragma unroll
  for (int j = 0; j < 8; ++j) m8[j] = fmaxf(fmaxf(a[j], b8[j]), fmaxf(c8[j], d8[j]));
  *(uint4*)(cat + (((size_t)bb * 4900 + (y + 3) * 70 + (xx2 + 3))) * 1536 + 1280 + cq * 8) = pack8(m8);
}

// --- haar DWT: rbn [16][128][128][64] -> CAT(padded) channels [0..256) -----
__global__ void k_haar(const unsigned short* __restrict__ rbn, unsigned short* __restrict__ cat) {
  int gid = blockIdx.x * 256 + threadIdx.x;        // 16*4096*8
  int cq = gid & 7; int pix = gid >> 3;
  int bb = pix >> 12; int yx = pix & 4095;
  int y = yx >> 6, xx = yx & 63;
  size_t base = (((size_t)bb * 128 + 2 * y) * 128 + 2 * xx) * 64 + cq * 8;
  uint4 va = *(const uint4*)(rbn + base);
  uint4 vb = *(const uint4*)(rbn + base + 64);
  uint4 vc = *(const uint4*)(rbn + base + 8192);
  uint4 vd = *(const uint4*)(rbn + base + 8192 + 64);
  float a[8], b8[8], c8[8], d8[8], o[8];
  unpack8(va, a); unpack8(vb, b8); unpack8(vc, c8); unpack8(vd, d8);
  size_t ob = ((size_t)bb * 4900 + (y + 3) * 70 + (xx + 3)) * 1536 + cq * 8;
  #pragma unroll
  for (int j = 0; j < 8; ++j) o[j] = (a[j] + b8[j] + c8[j] + d8[j]) * 0.5f;
  *(uint4*)(cat + ob + 0)   = pack8(o);
  #pragma unroll
  for (int j = 0; j < 8; ++j) o[j] = (a[j] + b8[j] - c8[j] - d8[j]) * 0.5f;
  *(uint4*)(cat + ob + 64)  = pack8(o);
  #pragma unroll
  for (int j = 0; j < 8; ++j) o[j] = (a[j] - b8[j] + c8[j] - d8[j]) * 0.5f;
  *(uint4*)(cat + ob + 128) = pack8(o);
  #pragma unroll
  for (int j = 0; j < 8; ++j) o[j] = (a[j] - b8[j] - c8[j] + d8[j]) * 0.5f;
  *(uint4*)(cat + ob + 192) = pack8(o);
}

// ===========================================================================
// 256x256 implicit-GEMM conv, 8 waves, BK=64, dbuf LDS (128KB), 4 phases.
// M fixed = 256 (Mpad=256), OW fixed = 64.  mode 0: bf16 NHWC store; mode 2:
// f32 NCHW store.  LDS chunk rotation: phys16Bchunk = (logical + row&7) & 7.
// ===========================================================================
__global__ __launch_bounds__(512, 2) void k_conv_gemm256(
    const unsigned short* __restrict__ Wt, const unsigned short* __restrict__ Bf,
    int Cin, int Cstr, int cbase,
    int PW, int PB, int KH, int pad,
    unsigned long long wbstride,
    unsigned short* __restrict__ outb, int OCstr, int ocbase, int OPW, int OPB,
    float* __restrict__ outf, int mode) {
  const int tid = threadIdx.x, lane = tid & 63, w = tid >> 6;
  const int wm = w >> 2, wn = w & 3;
  const int bn = blockIdx.x * 256;
  const int b = blockIdx.z;
  if (wbstride) Wt += (size_t)b * wbstride;
  extern __shared__ unsigned short S[];   // [2][A:16384][B:16384] shorts = 128KB

  f32x4 zero4 = {0.f, 0.f, 0.f, 0.f};
  f32x4 acc[8][4];
  #pragma unroll
  for (int i = 0; i < 8; ++i)
    #pragma unroll
    for (int j = 0; j < 4; ++j) acc[i][j] = zero4;

  // ---- staging (16B per lane per gload; instr j covers 8 rows x 128B) ----
  const int srow = lane >> 3;                       // 0..7
  const int csrc = ((lane & 7) - srow) & 7;         // inverse rotation
  const size_t jA = (size_t)8 * Cin;
  const unsigned short* aSt = Wt + ((size_t)(w * 32 + srow)) * Cin + csrc * 8;
  const size_t bimg = (size_t)b * PW * PW;
  const unsigned short* bSt[4];
  #pragma unroll
  for (int j = 0; j < 4; ++j) {
    int p = bn + w * 32 + j * 8 + srow;
    int y = p >> 6, x = p & 63;
    bSt[j] = Bf + (bimg + (size_t)(y + PB) * PW + (x + PB)) * Cstr + cbase + csrc * 8;
  }
  const int dstA = w * 2048;                        // shorts within buffer
  const int dstB = 16384 + w * 2048;

  // ---- fragment read offsets (shorts) ----
  const int r = lane & 15, s4 = lane >> 4;
  const int ck0 = (s4 + (r & 7)) & 7;               // phys chunk for kk=0
  const int dk1 = (ck0 < 4) ? 32 : -32;             // delta to kk=1 chunk
  const int aOff = (wm * 128 + r) * 64 + ck0 * 8;
  const int bOff = 16384 + (wn * 64 + r) * 64 + ck0 * 8;

  const size_t MC = (size_t)256 * Cin;
  const int NT = (KH * KH * Cin) >> 6;

  // ---- prologue: stage K-tile 0 into buffer 0 ----
  const long long pB0 = ((long long)(0 - pad) * PW + (0 - pad)) * (long long)Cstr;
  #pragma unroll
  for (int j = 0; j < 4; ++j) GLOAD16(aSt + (size_t)j * jA, S + dstA + j * 512);
  #pragma unroll
  for (int j = 0; j < 4; ++j) GLOAD16(bSt[j] + pB0, S + dstB + j * 512);
  __syncthreads();

  int kcn = 0, tyn = 0, txn = 0;                    // state of staged tile
  for (int kt = 0; kt < NT; ++kt) {
    const unsigned short* Sc = S + (kt & 1) * 32768;
    unsigned short* Sn = S + ((kt & 1) ^ 1) * 32768;
    const bool hn = (kt + 1 < NT);
    long long nA = 0, nB = 0;
    if (hn) {
      kcn += 64;
      if (kcn == Cin) { kcn = 0; ++txn; if (txn == KH) { txn = 0; ++tyn; } }
      nA = (long long)(tyn * KH + txn) * MC + kcn;
      nB = ((long long)(tyn - pad) * PW + (txn - pad)) * (long long)Cstr + kcn;
    }
    bf16x8 a[4], bb[4];
    // ------- phase 0: A(mi0-3,kk0)+B(kk0) reads; stage next A -------
    #pragma unroll
    for (int mi = 0; mi < 4; ++mi) a[mi] = *(const bf16x8*)(Sc + aOff + mi * 1024);
    #pragma unroll
    for (int ni = 0; ni < 4; ++ni) bb[ni] = *(const bf16x8*)(Sc + bOff + ni * 1024);
    if (hn) {
      #pragma unroll
      for (int j = 0; j < 4; ++j) GLOAD16(aSt + (size_t)j * jA + nA, Sn + dstA + j * 512);
    }
    __builtin_amdgcn_s_barrier();
    __builtin_amdgcn_s_setprio(1);
    #pragma unroll
    for (int mi = 0; mi < 4; ++mi)
      #pragma unroll
      for (int ni = 0; ni < 4; ++ni)
        acc[mi][ni] = __builtin_amdgcn_mfma_f32_16x16x32_bf16(a[mi], bb[ni], acc[mi][ni], 0, 0, 0);
    __builtin_amdgcn_s_setprio(0);
    __builtin_amdgcn_s_barrier();
    // ------- phase 1: A(mi4-7,kk0); stage next B -------
    #pragma unroll
    for (int mi = 0; mi < 4; ++mi) a[mi] = *(const bf16x8*)(Sc + aOff + (mi + 4) * 1024);
    if (hn) {
      #pragma unroll
      for (int j = 0; j < 4; ++j) GLOAD16(bSt[j] + nB, Sn + dstB + j * 512);
    }
    __builtin_amdgcn_s_barrier();
    __builtin_amdgcn_s_setprio(1);
    #pragma unroll
    for (int mi = 0; mi < 4; ++mi)
      #pragma unroll
      for (int ni = 0; ni < 4; ++ni)
        acc[mi + 4][ni] = __builtin_amdgcn_mfma_f32_16x16x32_bf16(a[mi], bb[ni], acc[mi + 4][ni], 0, 0, 0);
    __builtin_amdgcn_s_setprio(0);
    __builtin_amdgcn_s_barrier();
    // ------- phase 2: A(mi0-3,kk1)+B(kk1) -------
    #pragma unroll
    for (int mi = 0; mi < 4; ++mi) a[mi] = *(const bf16x8*)(Sc + aOff + mi * 1024 + dk1);
    #pragma unroll
    for (int ni = 0; ni < 4; ++ni) bb[ni] = *(const bf16x8*)(Sc + bOff + ni * 1024 + dk1);
    __builtin_amdgcn_s_barrier();
    __builtin_amdgcn_s_setprio(1);
    #pragma unroll
    for (int mi = 0; mi < 4; ++mi)
      #pragma unroll
      for (int ni = 0; ni < 4; ++ni)
        acc[mi][ni] = __builtin_amdgcn_mfma_f32_16x16x32_bf16(a[mi], bb[ni], acc[mi][ni], 0, 0, 0);
    __builtin_amdgcn_s_setprio(0);
    __builtin_amdgcn_s_barrier();
    // ------- phase 3: A(mi4-7,kk1); vmcnt(0) + handoff barrier -------
    #pragma unroll
    for (int mi = 0; mi < 4; ++mi) a[mi] = *(const bf16x8*)(Sc + aOff + (mi + 4) * 1024 + dk1);
    __builtin_amdgcn_s_barrier();
    __builtin_amdgcn_s_setprio(1);
    #pragma unroll
    for (int mi = 0; mi < 4; ++mi)
      #pragma unroll
      for (int ni = 0; ni < 4; ++ni)
        acc[mi + 4][ni] = __builtin_amdgcn_mfma_f32_16x16x32_bf16(a[mi], bb[ni], acc[mi + 4][ni], 0, 0, 0);
    __builtin_amdgcn_s_setprio(0);
    asm volatile("s_waitcnt vmcnt(0)" ::: "memory");
    __builtin_amdgcn_s_barrier();
  }

  // ---- epilogue ----
  const size_t bimgO = (size_t)b * OPW * OPW;
  #pragma unroll
  for (int mi = 0; mi < 8; ++mi) {
    const int mf = wm * 128 + mi * 16 + (lane >> 4) * 4;
    #pragma unroll
    for (int ni = 0; ni < 4; ++ni) {
      const int n = bn + wn * 64 + ni * 16 + (lane & 15);
      if (mode == 2) {
        #pragma unroll
        for (int vv = 0; vv < 4; ++vv)
          outf[((size_t)b * 256 + mf + vv) * 4096 + n] = acc[mi][ni][vv];
      } else {
        const int oy = n >> 6, ox = n & 63;
        unsigned short h[4];
        #pragma unroll
        for (int vv = 0; vv < 4; ++vv) h[vv] = f2bf(acc[mi][ni][vv]);
        uint2 st; st.x = (unsigned)h[0] | ((unsigned)h[1] << 16);
        st.y = (unsigned)h[2] | ((unsigned)h[3] << 16);
        *(uint2*)&outb[(bimgO + (size_t)(oy + OPB) * OPW + (ox + OPB)) * OCstr + ocbase + mf] = st;
      }
    }
  }
}

// --- 128^2 implicit-GEMM conv (kept for M=64 reduce conv, mode 1) ----------
__global__ __launch_bounds__(256) void k_conv_gemm(
    const unsigned short* __restrict__ Wt, const unsigned short* __restrict__ Bf,
    int M, int Mpad, int Cin, int Cstr, int cbase,
    int OW, int lgOW, int PW, int PB, int KH, int pad,
    unsigned long long wbstride,
    unsigned short* __restrict__ outb, int OCstr, int ocbase, int OPW, int OPB,
    float* __restrict__ outf, int mode,
    const float* __restrict__ rb, const float* __restrict__ bng, const float* __restrict__ bnb,
    const float* __restrict__ bnm, const float* __restrict__ bnv) {
  const int tid = threadIdx.x, lane = tid & 63, w = tid >> 6;
  const int wm = w >> 1, wn = w & 1;
  const int bm = blockIdx.y * 128, bn = blockIdx.x * 128;
  const int b = blockIdx.z;
  const int Npix = OW * OW;
  if (wbstride) Wt += (size_t)b * wbstride;

  __shared__ __align__(1024) unsigned short sA[128 * 32];
  __shared__ __align__(1024) unsigned short sB[128 * 32];

  f32x4 zero4 = {0.f, 0.f, 0.f, 0.f};
  f32x4 acc[4][4];
  #pragma unroll
  for (int i = 0; i < 4; ++i)
    #pragma unroll
    for (int j = 0; j < 4; ++j) acc[i][j] = zero4;

  const int srow = lane >> 2;
  const int slog = (lane & 3) ^ ((lane >> 3) & 3);
  const int r0 = w * 32;
  const unsigned short* aRow = Wt + ((size_t)(bm + r0 + srow)) * Cin + slog * 8;
  const int n0 = bn + r0 + srow, n1 = n0 + 16;
  const int y0 = n0 >> lgOW, x0 = n0 & (OW - 1);
  const int y1 = n1 >> lgOW, x1 = n1 & (OW - 1);
  const size_t bimg = (size_t)b * PW * PW;
  const unsigned short* bRow0 = Bf + (bimg + (size_t)(y0 + PB) * PW + (x0 + PB)) * Cstr + cbase + slog * 8;
  const unsigned short* bRow1 = Bf + (bimg + (size_t)(y1 + PB) * PW + (x1 + PB)) * Cstr + cbase + slog * 8;
  unsigned short* ldsA0 = &sA[(r0) * 32];
  unsigned short* ldsA1 = &sA[(r0 + 16) * 32];
  unsigned short* ldsB0 = &sB[(r0) * 32];
  unsigned short* ldsB1 = &sB[(r0 + 16) * 32];

  const int rowfrag = lane & 15, hi = lane >> 4;
  const int sl = hi ^ ((rowfrag >> 1) & 3);
  const bf16x8* pA[4]; const bf16x8* pB[4];
  #pragma unroll
  for (int mi = 0; mi < 4; ++mi)
    pA[mi] = (const bf16x8*)&sA[(wm * 64 + mi * 16 + rowfrag) * 32 + sl * 8];
  #pragma unroll
  for (int ni = 0; ni < 4; ++ni)
    pB[ni] = (const bf16x8*)&sB[(wn * 64 + ni * 16 + rowfrag) * 32 + sl * 8];

  const size_t MC = (size_t)Mpad * Cin;
  for (int ty = 0; ty < KH; ++ty) {
    for (int tx = 0; tx < KH; ++tx) {
      const unsigned short* at = aRow + (size_t)(ty * KH + tx) * MC;
      const long long toff = ((long long)(ty - pad) * PW + (tx - pad)) * Cstr;
      const unsigned short* bt0 = bRow0 + toff;
      const unsigned short* bt1 = bRow1 + toff;
      for (int kc = 0; kc < Cin; kc += 32) {
        GLOAD16(at + kc, ldsA0);
        GLOAD16(at + (size_t)16 * Cin + kc, ldsA1);
        GLOAD16(bt0 + kc, ldsB0);
        GLOAD16(bt1 + kc, ldsB1);
        __syncthreads();
        bf16x8 af[4], bfr[4];
        #pragma unroll
        for (int mi = 0; mi < 4; ++mi) af[mi] = *pA[mi];
        #pragma unroll
        for (int ni = 0; ni < 4; ++ni) bfr[ni] = *pB[ni];
        #pragma unroll
        for (int mi = 0; mi < 4; ++mi)
          #pragma unroll
          for (int ni = 0; ni < 4; ++ni)
            acc[mi][ni] = __builtin_amdgcn_mfma_f32_16x16x32_bf16(af[mi], bfr[ni], acc[mi][ni], 0, 0, 0);
        __syncthreads();
      }
    }
  }

  const int mb0 = bm + wm * 64, nb0 = bn + wn * 64;
  const size_t bimgO = (size_t)b * OPW * OPW;
  #pragma unroll
  for (int mi = 0; mi < 4; ++mi) {
    const int mf = mb0 + mi * 16 + (lane >> 4) * 4;
    if (mf >= M) continue;
    #pragma unroll
    for (int ni = 0; ni < 4; ++ni) {
      const int n = nb0 + ni * 16 + (lane & 15);
      if (mode == 2) {
        #pragma unroll
        for (int vv = 0; vv < 4; ++vv)
          outf[((size_t)b * M + mf + vv) * Npix + n] = acc[mi][ni][vv];
      } else {
        const int oy = n >> lgOW, ox = n & (OW - 1);
        unsigned short h[4];
        #pragma unroll
        for (int vv = 0; vv < 4; ++vv) {
          float val = acc[mi][ni][vv];
          if (mode == 1) {
            int m = mf + vv;
            float scl = bng[m] * rsqrtf(bnv[m] + EPS_);
            val = (val + rb[m] - bnm[m]) * scl + bnb[m];
            val = fmaxf(val, 0.f);
          }
          h[vv] = f2bf(val);
        }
        uint2 st; st.x = (unsigned)h[0] | ((unsigned)h[1] << 16);
        st.y = (unsigned)h[2] | ((unsigned)h[3] << 16);
        *(uint2*)&outb[(bimgO + (size_t)(oy + OPB) * OPW + (ox + OPB)) * OCstr + ocbase + mf] = st;
      }
    }
  }
}

// --- content logits: dot(qkv[pix], w) over 256 ch --------------------------
__global__ void k_content_logits(const unsigned short* __restrict__ qkv,
                                 const float* __restrict__ conv_w,
                                 float* __restrict__ logits) {
  int j = blockIdx.x, b = blockIdx.y, tid = threadIdx.x;
  __shared__ float wl[256];
  wl[tid] = conv_w[tid];
  __syncthreads();
  int pl = tid >> 3, kp = tid & 7;
  #pragma unroll
  for (int pass = 0; pass < 4; ++pass) {
    int p = j * 128 + pass * 32 + pl;
    int y = p >> 6, x = p & 63;
    const unsigned short* q = qkv + (((size_t)b * 66 + y + 1) * 66 + (x + 1)) * 256 + kp * 32;
    float s = 0.f;
    #pragma unroll
    for (int i = 0; i < 32; i += 8) {
      uint4 v = *(const uint4*)(q + i);
      float f[8]; unpack8(v, f);
      #pragma unroll
      for (int k = 0; k < 8; ++k) s += f[k] * wl[kp * 32 + i + k];
    }
    s += __shfl_down(s, 4, 8);
    s += __shfl_down(s, 2, 8);
    s += __shfl_down(s, 1, 8);
    if (kp == 0) logits[(size_t)b * 4096 + p] = s;
  }
}

// --- softmax over 4096 per batch (in place) --------------------------------
__global__ void k_softmax4096(float* __restrict__ cont) {
  int b = blockIdx.x, tid = threadIdx.x;
  __shared__ float red[256];
  float sv[16]; float mx = -1e30f;
  #pragma unroll
  for (int j = 0; j < 16; ++j) { sv[j] = cont[(size_t)b * 4096 + j * 256 + tid]; mx = fmaxf(mx, sv[j]); }
  red[tid] = mx; __syncthreads();
  for (int s = 128; s > 0; s >>= 1) { if (tid < s) red[tid] = fmaxf(red[tid], red[tid + s]); __syncthreads(); }
  mx = red[0]; __syncthreads();
  float sum = 0.f;
  #pragma unroll
  for (int j = 0; j < 16; ++j) { sv[j] = expf(sv[j] - mx); sum += sv[j]; }
  red[tid] = sum; __syncthreads();
  for (int s = 128; s > 0; s >>= 1) { if (tid < s) red[tid] += red[tid + s]; __syncthreads(); }
  float inv = 1.f / red[0];
  #pragma unroll
  for (int j = 0; j < 16; ++j) cont[(size_t)b * 4096 + j * 256 + tid] = sv[j] * inv;
}

// --- pooled partials ---
__global__ void k_pooled_part(const unsigned short* __restrict__ chn,
                              const float* __restrict__ content, float* __restrict__ ppart) {
  int j = blockIdx.x, b = blockIdx.y, c = threadIdx.x;
  const unsigned short* base = chn + (size_t)b * 4096 * 256 + c;
  const float* ct = content + (size_t)b * 4096;
  float acc = 0.f;
  int n0 = j * 128;
  for (int n = n0; n < n0 + 128; ++n)
    acc += bf2f(base[(size_t)n * 256]) * ct[n];
  ppart[((size_t)b * 32 + j) * 256 + c] = acc;
}
__global__ void k_pooled_red(const float* __restrict__ ppart, float* __restrict__ pooled) {
  int b = blockIdx.x, c = threadIdx.x;
  float s = 0.f;
  #pragma unroll
  for (int j = 0; j < 32; ++j) s += ppart[((size_t)b * 32 + j) * 256 + c];
  pooled[b * 256 + c] = s;
}

// --- ct1 -> LN -> relu -> ct2 ----------------------------------------------
__global__ void k_ct(const float* __restrict__ pooled,
                     const float* __restrict__ ct1w, const float* __restrict__ ct1b,
                     const float* __restrict__ lng, const float* __restrict__ lnb,
                     const float* __restrict__ ct2w, const float* __restrict__ ct2b,
                     float* __restrict__ cw) {
  int b = blockIdx.x, tid = threadIdx.x;
  __shared__ float tt[32];
  __shared__ float stats[2];
  if (tid < 32) {
    float s = 0.f;
    const float* w = ct1w + tid * 256;
    const float* p = pooled + b * 256;
    for (int i = 0; i < 256; ++i) s += w[i] * p[i];
    tt[tid] = s + ct1b[tid];
  }
  __syncthreads();
  if (tid == 0) {
    float mu = 0.f;
    for (int j = 0; j < 32; ++j) mu += tt[j];
    mu *= (1.f / 32.f);
    float va = 0.f;
    for (int j = 0; j < 32; ++j) { float d = tt[j] - mu; va += d * d; }
    va *= (1.f / 32.f);
    stats[0] = mu; stats[1] = rsqrtf(va + EPS_);
  }
  __syncthreads();
  if (tid < 32) {
    float v = (tt[tid] - stats[0]) * stats[1];
    tt[tid] = fmaxf(v * lng[tid] + lnb[tid], 0.f);
  }
  __syncthreads();
  float s = 0.f;
  const float* w2 = ct2w + tid * 32;
  #pragma unroll
  for (int j = 0; j < 32; ++j) s += w2[j] * tt[j];
  cw[b * 256 + tid] = s + ct2b[tid];
}

// --- per-batch proj weights ------------------------------------------------
__global__ void k_aproj(const float* __restrict__ projw, const float* __restrict__ cw,
                        unsigned short* __restrict__ aproj) {
  int gid = blockIdx.x * 256 + threadIdx.x;   // 16*65536
  int b = gid >> 16; int oi = gid & 65535; int i = oi & 255;
  aproj[gid] = f2bf(projw[oi] * cw[b * 256 + i]);
}

extern "C" void kernel_launch(void* const* d_in, const int* in_sizes, int n_in,
                              void* d_out, int out_size, void* d_ws, size_t ws_size,
                              hipStream_t stream) {
  (void)in_sizes; (void)n_in; (void)out_size; (void)ws_size;
  const float* x        = (const float*)d_in[0];
  const float* reduce_w = (const float*)d_in[1];
  const float* reduce_b = (const float*)d_in[2];
  const float* bn_g     = (const float*)d_in[3];
  const float* bn_b     = (const float*)d_in[4];
  const float* bn_mean  = (const float*)d_in[5];
  const float* bn_var   = (const float*)d_in[6];
  const float* conv_w   = (const float*)d_in[7];
  const float* conv1_w  = (const float*)d_in[8];
  const float* conv2_w  = (const float*)d_in[9];
  const float* conv3_w  = (const float*)d_in[10];
  const float* conv4_w  = (const float*)d_in[11];
  const float* chconv_w = (const float*)d_in[12];
  const float* cat_w    = (const float*)d_in[13];
  const float* ct1_w    = (const float*)d_in[14];
  const float* ct1_b    = (const float*)d_in[15];
  const float* ln_g     = (const float*)d_in[16];
  const float* ln_b     = (const float*)d_in[17];
  const float* ct2_w    = (const float*)d_in[18];
  const float* ct2_b    = (const float*)d_in[19];
  const float* proj_w   = (const float*)d_in[20];

  static bool attr_done = false;
  if (!attr_done) {
    hipFuncSetAttribute(reinterpret_cast<const void*>(&k_conv_gemm256),
                        hipFuncAttributeMaxDynamicSharedMemorySize, 131072);
    attr_done = true;
  }

  char* wsp = (char*)d_ws;
  size_t off = 0;
  auto alloc = [&](size_t bytes) -> char* {
    char* p = wsp + off; off += (bytes + 255) & ~(size_t)255; return p;
  };
  unsigned short* XH    = (unsigned short*)alloc((size_t)16 * 16384 * 256 * 2); // 134MB
  unsigned short* CAT   = (unsigned short*)alloc((size_t)16 * 4900 * 1536 * 2); // 241MB
  unsigned short* RBN   = (unsigned short*)alloc((size_t)16 * 16384 * 64 * 2);  // 33.5MB
  unsigned short* CHN   = RBN;  // disjoint lifetimes
  unsigned short* QKV   = (unsigned short*)alloc((size_t)16 * 4356 * 256 * 2);  // 35.7MB
  float*          CONT  = (float*)alloc((size_t)16 * 4096 * 4);
  float*          PPART = (float*)alloc((size_t)16 * 32 * 256 * 4);
  float*          POOL  = (float*)alloc(16 * 256 * 4);
  float*          CWB   = (float*)alloc(16 * 256 * 4);
  unsigned short* WR    = (unsigned short*)alloc((size_t)128 * 256 * 2);
  unsigned short* W1    = (unsigned short*)alloc((size_t)256 * 256 * 2);
  unsigned short* W2    = (unsigned short*)alloc((size_t)9 * 256 * 256 * 2);
  unsigned short* W3    = (unsigned short*)alloc((size_t)25 * 256 * 256 * 2);
  unsigned short* W4    = (unsigned short*)alloc((size_t)49 * 256 * 256 * 2);
  unsigned short* WC    = (unsigned short*)alloc((size_t)9 * 256 * 256 * 2);
  unsigned short* WCAT  = (unsigned short*)alloc((size_t)9 * 256 * 1536 * 2);
  unsigned short* APROJ = (unsigned short*)alloc((size_t)16 * 256 * 256 * 2);

  auto rp = [&](const float* s, unsigned short* d, int O, int Opad, int I, int T) {
    int tot = Opad * I * T;
    k_repack<<<(tot + 255) / 256, 256, 0, stream>>>(s, d, O, Opad, I, T);
  };
  rp(reduce_w, WR, 64, 128, 256, 1);
  rp(conv1_w, W1, 256, 256, 256, 1);
  rp(conv2_w, W2, 256, 256, 256, 9);
  rp(conv3_w, W3, 256, 256, 256, 25);
  rp(conv4_w, W4, 256, 256, 256, 49);
  rp(chconv_w, WC, 256, 256, 256, 9);
  rp(cat_w, WCAT, 256, 256, 1536, 9);

  k_border_zero<<<(16 * 804 * 192 + 255) / 256, 256, 0, stream>>>(CAT, 70, 3, 1536);
  k_border_zero<<<(16 * 260 * 32 + 255) / 256, 256, 0, stream>>>(QKV, 66, 1, 256);

  k_transpose_x<<<2048, 256, 0, stream>>>(x, XH);
  k_maxpool<<<8192, 256, 0, stream>>>(XH, CAT);

  dim3 blk(256);
  dim3 g256(16, 1, 16);
  // reduce conv 1x1 (256->64 @128x128, Mpad=128) + BN + relu -> RBN
  k_conv_gemm<<<dim3(128, 1, 16), blk, 0, stream>>>(WR, XH, 64, 128, 256, 256, 0,
      128, 7, 128, 0, 1, 0, 0ULL, RBN, 64, 0, 128, 0, nullptr, 1,
      reduce_b, bn_g, bn_b, bn_mean, bn_var);
  k_haar<<<2048, 256, 0, stream>>>(RBN, CAT);
  // branch convs on qkv0 (CAT ch[0:256)) -> CAT slices
  k_conv_gemm256<<<g256, 512, 131072, stream>>>(W1, CAT, 256, 1536, 0,
      70, 3, 1, 0, 0ULL, CAT, 1536, 256, 70, 3, nullptr, 0);
  k_conv_gemm256<<<g256, 512, 131072, stream>>>(W2, CAT, 256, 1536, 0,
      70, 3, 3, 1, 0ULL, CAT, 1536, 512, 70, 3, nullptr, 0);
  k_conv_gemm256<<<g256, 512, 131072, stream>>>(W3, CAT, 256, 1536, 0,
      70, 3, 5, 2, 0ULL, CAT, 1536, 768, 70, 3, nullptr, 0);
  k_conv_gemm256<<<g256, 512, 131072, stream>>>(W4, CAT, 256, 1536, 0,
      70, 3, 7, 3, 0ULL, CAT, 1536, 1024, 70, 3, nullptr, 0);
  // big conv: 3x3 1536->256 over CAT -> QKV (padded 66x66)
  k_conv_gemm256<<<g256, 512, 131072, stream>>>(WCAT, CAT, 1536, 1536, 0,
      70, 3, 3, 1, 0ULL, QKV, 256, 0, 66, 1, nullptr, 0);
  k_content_logits<<<dim3(32, 16), blk, 0, stream>>>(QKV, conv_w, CONT);
  k_softmax4096<<<16, blk, 0, stream>>>(CONT);
  // channel conv: 3x3 256->256 over QKV -> CHN (unpadded)
  k_conv_gemm256<<<g256, 512, 131072, stream>>>(WC, QKV, 256, 256, 0,
      66, 1, 3, 1, 0ULL, CHN, 256, 0, 64, 0, nullptr, 0);
  k_pooled_part<<<dim3(32, 16), blk, 0, stream>>>(CHN, CONT, PPART);
  k_pooled_red<<<16, blk, 0, stream>>>(PPART, POOL);
  k_ct<<<16, blk, 0, stream>>>(POOL, ct1_w, ct1_b, ln_g, ln_b, ct2_w, ct2_b, CWB);
  k_aproj<<<4096, 256, 0, stream>>>(proj_w, CWB, APROJ);
  // proj: per-batch A' = proj_w * cw, 1x1 over QKV -> d_out f32 NCHW
  k_conv_gemm256<<<g256, 512, 131072, stream>>>(APROJ, QKV, 256, 256, 0,
      66, 1, 1, 0, 65536ULL, nullptr, 256, 0, 64, 0, (float*)d_out, 2);
}